// Round 10
// baseline (2175.595 us; speedup 1.0000x reference)
//
#include <hip/hip_runtime.h>
#include <hip/hip_bf16.h>
#include <math.h>

// Problem: S=512, B=128, V=50257, D=300, H=512
#define S_LEN 512
#define B_N   128
#define D_EMB 300
#define KP    320   // D padded to multiple of 32 (zero-filled)
#define H_N   512

typedef __attribute__((ext_vector_type(8)))  short short8;       // 8 bf16 (4 VGPRs)
typedef __attribute__((ext_vector_type(8)))  unsigned short ushort8;
typedef __attribute__((ext_vector_type(4)))  float float4v;
typedef __attribute__((ext_vector_type(16))) float float16v;

__device__ __forceinline__ unsigned short f32_to_bf16(float f) {
  unsigned u = __float_as_uint(f);
  u = (u + 0x7fffu + ((u >> 16) & 1u)) >> 16;   // RNE
  return (unsigned short)u;
}
__device__ __forceinline__ float bf16_to_f32(unsigned short h) {
  return __uint_as_float(((unsigned)h) << 16);
}

// ---------------------------------------------------------------------------
// K1: embeds = embed_mat[ends]; xn = embeds / max(||embeds||,eps)
// writes xn as split bf16 (hi+lo), layout [b][s][KP], k 300..319 zero.
// ---------------------------------------------------------------------------
__global__ __launch_bounds__(256) void k1_embed_norm(
    const int* __restrict__ ends, const float* __restrict__ emb,
    unsigned short* __restrict__ xh, unsigned short* __restrict__ xl) {
  int wave = threadIdx.x >> 6, lane = threadIdx.x & 63;
  int vec = blockIdx.x * 4 + wave;            // vec = s*B + b (ends is [S][B])
  int b = vec & (B_N - 1), s = vec >> 7;
  int v = ends[vec];
  const float* row = emb + (size_t)v * D_EMB;
  float e0 = row[lane], e1 = row[lane + 64], e2 = row[lane + 128], e3 = row[lane + 192];
  float e4 = (lane + 256 < D_EMB) ? row[lane + 256] : 0.f;
  float ss = e0*e0 + e1*e1 + e2*e2 + e3*e3 + e4*e4;
  #pragma unroll
  for (int m = 1; m < 64; m <<= 1) ss += __shfl_xor(ss, m);
  float sc = 1.0f / fmaxf(sqrtf(ss), 1e-8f);
  size_t base = ((size_t)b * S_LEN + s) * KP;
  float xs[5] = { e0*sc, e1*sc, e2*sc, e3*sc, (lane + 256 < D_EMB) ? e4*sc : 0.f };
  #pragma unroll
  for (int i = 0; i < 5; ++i) {
    unsigned short hi = f32_to_bf16(xs[i]);
    unsigned short lo = f32_to_bf16(xs[i] - bf16_to_f32(hi));
    xh[base + lane + 64*i] = hi;
    xl[base + lane + 64*i] = lo;
  }
}

// ---------------------------------------------------------------------------
// K2: feats[i][b] = max_{j<i} dot(xn[i,b], xn[j,b]); feats[0]=0
// Split-bf16 MFMA 32x32x16 (hi*hi + hi*lo + lo*hi).
// ---------------------------------------------------------------------------
#define KC  80
#define LDP 88      // LDS row stride in ushorts (conflict-friendly, 16B aligned)

__global__ __launch_bounds__(256) void k2_feats(
    const unsigned short* __restrict__ xh, const unsigned short* __restrict__ xl,
    float* __restrict__ feats) {
  __shared__ __align__(16) unsigned short sAh[64*LDP], sAl[64*LDP], sBh[64*LDP], sBl[64*LDP];
  __shared__ float rbuf[4][32];
  int ic  = blockIdx.x;          // 0..7
  int b   = blockIdx.y;          // 0..127
  int tid = threadIdx.x;
  int wave = tid >> 6, lane = tid & 63;
  int itl = wave & 1, jtl = wave >> 1;
  int itg = ic * 2 + itl;        // global 32-row i-tile index
  size_t xbase = (size_t)b * S_LEN * KP;
  int arow0 = ic * 64;

  float rm[16];
  #pragma unroll
  for (int r = 0; r < 16; ++r) rm[r] = -INFINITY;

  for (int jc = 0; jc <= ic; ++jc) {
    int jt = jc * 2 + jtl;
    bool active = (jt <= itg);
    float16v acc;
    #pragma unroll
    for (int r = 0; r < 16; ++r) acc[r] = 0.f;

    for (int kc = 0; kc < 4; ++kc) {
      __syncthreads();
      for (int u = tid; u < 640; u += 256) {     // 64 rows x 10 16B-segs
        int r = u / 10, sg = u % 10;
        size_t ga = xbase + (size_t)(arow0 + r) * KP + kc*KC + sg*8;
        size_t gb = xbase + (size_t)(jc*64 + r) * KP + kc*KC + sg*8;
        int la = r * LDP + sg * 8;
        *(ushort8*)&sAh[la] = *(const ushort8*)&xh[ga];
        *(ushort8*)&sAl[la] = *(const ushort8*)&xl[ga];
        *(ushort8*)&sBh[la] = *(const ushort8*)&xh[gb];
        *(ushort8*)&sBl[la] = *(const ushort8*)&xl[gb];
      }
      __syncthreads();
      if (active) {
        int ar = (itl*32 + (lane & 31)) * LDP;
        int br = (jtl*32 + (lane & 31)) * LDP;
        int kq = (lane >> 5) * 8;
        #pragma unroll
        for (int ks = 0; ks < 5; ++ks) {
          short8 a_h = *(const short8*)&sAh[ar + ks*16 + kq];
          short8 a_l = *(const short8*)&sAl[ar + ks*16 + kq];
          short8 b_h = *(const short8*)&sBh[br + ks*16 + kq];
          short8 b_l = *(const short8*)&sBl[br + ks*16 + kq];
          acc = __builtin_amdgcn_mfma_f32_32x32x16_bf16(a_h, b_h, acc, 0, 0, 0);
          acc = __builtin_amdgcn_mfma_f32_32x32x16_bf16(a_h, b_l, acc, 0, 0, 0);
          acc = __builtin_amdgcn_mfma_f32_32x32x16_bf16(a_l, b_h, acc, 0, 0, 0);
        }
      }
    }
    if (active) {
      int colg = jt * 32 + (lane & 31);
      #pragma unroll
      for (int r = 0; r < 16; ++r) {
        int rowg = itg * 32 + (r & 3) + 8*(r >> 2) + 4*(lane >> 5);
        float v = acc[r];
        if (jt == itg && colg >= rowg) v = -INFINITY;  // causal: j<i
        rm[r] = fmaxf(rm[r], v);
      }
    }
  }
  #pragma unroll
  for (int r = 0; r < 16; ++r) {
    float v = rm[r];
    v = fmaxf(v, __shfl_xor(v, 1));
    v = fmaxf(v, __shfl_xor(v, 2));
    v = fmaxf(v, __shfl_xor(v, 4));
    v = fmaxf(v, __shfl_xor(v, 8));
    v = fmaxf(v, __shfl_xor(v, 16));
    rm[r] = v;
  }
  if ((lane & 31) == 0) {
    int half = lane >> 5;
    #pragma unroll
    for (int r = 0; r < 16; ++r)
      rbuf[wave][(r & 3) + 8*(r >> 2) + 4*half] = rm[r];
  }
  __syncthreads();
  if (tid < 64) {   // merge jt-parities, write feats
    int it2 = tid >> 5, rl = tid & 31;
    float v = fmaxf(rbuf[it2][rl], rbuf[it2 + 2][rl]);
    int i = ic * 64 + it2 * 32 + rl;
    feats[i * B_N + b] = (i == 0) ? 0.0f : v;
  }
}

// ---------------------------------------------------------------------------
// K3: GRU, persistent cooperative kernel. 256 WGs x 256 thr.
// Transport (R8-PROVEN): wg-scope producer stores -> dirty in shared XCD L2
// (WRITE_SIZE 135MB->0.5MB); agent-scope relaxed reads (L1-bypass, L2-hit).
// Sync (R10): R8's 32 per-WG flag WORDS kept (proven read structure), but
// each word is now a COUNTER incremented once per wave (atomicAdd wg-scope
// after own vmcnt(0) drain) — removes the post-store __syncthreads.
// Counter == 4t  <=>  all 4 waves of that WG finished step t-1.
// Per-lane poll target: 4t for my 8 data-producer WGs ((lane&31)>>3 ==
// wave), 4(t-1) for the rest (WAR only — enabled by TRIPLE-buffered hq:
// write t%3, read (t-1)%3; overwritten buffer was last read at t-2).
// red[] parity-buffered -> single __syncthreads per step (the step-t
// barrier fences step t-1's reads; parities never collide).
// NOTE: per-WAVE flag addresses (128/group) fast-failed 3/3 (R5/R6/R9,
// mechanism unknown) — do not reintroduce.
// ---------------------------------------------------------------------------
#define HW64 (B_N * H_N / 2)   // 8B words per buffer

__global__ __launch_bounds__(256, 1) void k3_gru(
    const float* __restrict__ feats,
    const float* __restrict__ w_ih, const float* __restrict__ w_hh,
    const float* __restrict__ b_ih, const float* __restrict__ b_hh,
    const float* __restrict__ fc_w, const float* __restrict__ fc_b,
    unsigned long long* __restrict__ hq, unsigned int* __restrict__ bars,
    float* __restrict__ out) {
  __shared__ float red[2][4][3][16][17];   // [parity][wave][gate][b][j]
  __shared__ float osum[256];
  int tid = threadIdx.x;
  int wave = tid >> 6, lane = tid & 63;
  int g = blockIdx.x & 7, s = blockIdx.x >> 3;

  // --- stationary W_hh fragments in registers (B-operand: n=lane&15, k=quad*8+j)
  short8 wfh[3][4], wfl[3][4];
  {
    int nloc = lane & 15;
    int kq = (lane >> 4) * 8;
    #pragma unroll
    for (int gt = 0; gt < 3; ++gt) {
      const float* wr = w_hh + (size_t)(gt * H_N + s * 16 + nloc) * H_N;
      #pragma unroll
      for (int ks = 0; ks < 4; ++ks) {
        int k0 = wave * 128 + ks * 32 + kq;
        short8 h8, l8;
        #pragma unroll
        for (int j = 0; j < 8; ++j) {
          float wv = wr[k0 + j];
          unsigned short hi = f32_to_bf16(wv);
          unsigned short lo = f32_to_bf16(wv - bf16_to_f32(hi));
          h8[j] = (short)hi; l8[j] = (short)lo;
        }
        wfh[gt][ks] = h8; wfl[gt][ks] = l8;
      }
    }
  }
  // --- per-thread gate constants: thread = (bb, jj)
  int bb = tid >> 4, jj = tid & 15;
  int jr = s * 16 + jj;
  float wihr = w_ih[jr], wihz = w_ih[H_N + jr], wihn = w_ih[2*H_N + jr];
  float bir = b_ih[jr],  biz = b_ih[H_N + jr],  bin_ = b_ih[2*H_N + jr];
  float bhr = b_hh[jr],  bhz = b_hh[H_N + jr],  bhn = b_hh[2*H_N + jr];
  float fcw = fc_w[jr];
  int gb = g * 16 + bb;
  float h_old = 0.f;
  const unsigned int* fp = bars + g * 32 + (lane & 31);  // R8-proven poll set
  unsigned int* mycnt = bars + g * 32 + s;
  // poll target offset: 0 for my data producers, 4 (one step lag) for WAR-only
  unsigned tgtoff = (((lane & 31) >> 3) == wave) ? 0u : 4u;
  int arow = g * 16 + (lane & 15);              // A-operand m = batch
  int kqa = (lane >> 4) * 8;
  size_t widx = ((size_t)gb * H_N + jr) >> 1;   // 8B word index (jj even only)
  int wr3 = 0, rd3 = 2;                         // t%3 and (t-1)%3

  for (int t = 0; t < S_LEN; ++t) {
    // feats load hoisted above the poll — independent, overlaps the spin
    float x = feats[t * B_N + gb];
    float sr = 0.f, sz = 0.f, sn = 0.f;
    if (t > 0) {
      // ---- wait: my 8 producer WGs at 4t; all others at 4(t-1) (WAR)
      {
        const unsigned tgt = 4u * (unsigned)t - tgtoff;
        for (;;) {
          unsigned f = __hip_atomic_load(fp, __ATOMIC_RELAXED, __HIP_MEMORY_SCOPE_AGENT);
          if (__ballot(f < tgt) == 0ull) break;
          __builtin_amdgcn_s_sleep(1);
        }
        asm volatile("" ::: "memory");
      }
      const unsigned long long* hb =
          hq + (size_t)rd3 * HW64 + (size_t)arow * (H_N / 2);
      short8 ah[4], al[4];
      #pragma unroll
      for (int ks = 0; ks < 4; ++ks) {
        int kw = (wave * 128 + ks * 32 + kqa) >> 1;
        union { unsigned u[4]; short8 v; } uh, ul;
        #pragma unroll
        for (int q = 0; q < 4; ++q) {
          unsigned long long w = __hip_atomic_load(hb + kw + q,
              __ATOMIC_RELAXED, __HIP_MEMORY_SCOPE_AGENT);
          uh.u[q] = (unsigned)w;
          ul.u[q] = (unsigned)(w >> 32);
        }
        ah[ks] = uh.v; al[ks] = ul.v;
      }
      float4v a0, a1, a2;
      #pragma unroll
      for (int r = 0; r < 4; ++r) { a0[r] = 0.f; a1[r] = 0.f; a2[r] = 0.f; }
      #pragma unroll
      for (int ks = 0; ks < 4; ++ks) {
        a0 = __builtin_amdgcn_mfma_f32_16x16x32_bf16(ah[ks], wfh[0][ks], a0, 0,0,0);
        a1 = __builtin_amdgcn_mfma_f32_16x16x32_bf16(ah[ks], wfh[1][ks], a1, 0,0,0);
        a2 = __builtin_amdgcn_mfma_f32_16x16x32_bf16(ah[ks], wfh[2][ks], a2, 0,0,0);
        a0 = __builtin_amdgcn_mfma_f32_16x16x32_bf16(ah[ks], wfl[0][ks], a0, 0,0,0);
        a1 = __builtin_amdgcn_mfma_f32_16x16x32_bf16(ah[ks], wfl[1][ks], a1, 0,0,0);
        a2 = __builtin_amdgcn_mfma_f32_16x16x32_bf16(ah[ks], wfl[2][ks], a2, 0,0,0);
        a0 = __builtin_amdgcn_mfma_f32_16x16x32_bf16(al[ks], wfh[0][ks], a0, 0,0,0);
        a1 = __builtin_amdgcn_mfma_f32_16x16x32_bf16(al[ks], wfh[1][ks], a1, 0,0,0);
        a2 = __builtin_amdgcn_mfma_f32_16x16x32_bf16(al[ks], wfh[2][ks], a2, 0,0,0);
      }
      // C/D: row(batch)=(lane>>4)*4+reg, col(j)=lane&15. Parity buffer.
      int par = t & 1;
      int colw = lane & 15, roww = (lane >> 4) * 4;
      #pragma unroll
      for (int r = 0; r < 4; ++r) {
        red[par][wave][0][roww + r][colw] = a0[r];
        red[par][wave][1][roww + r][colw] = a1[r];
        red[par][wave][2][roww + r][colw] = a2[r];
      }
      __syncthreads();
      sr = red[par][0][0][bb][jj] + red[par][1][0][bb][jj] + red[par][2][0][bb][jj] + red[par][3][0][bb][jj];
      sz = red[par][0][1][bb][jj] + red[par][1][1][bb][jj] + red[par][2][1][bb][jj] + red[par][3][1][bb][jj];
      sn = red[par][0][2][bb][jj] + red[par][1][2][bb][jj] + red[par][2][2][bb][jj] + red[par][3][2][bb][jj];
    }
    // gates: exact identities on fast exp; clamp to dodge inf/inf
    float ar_ = fminf(fmaxf(x * wihr + bir + sr + bhr, -30.f), 30.f);
    float az_ = fminf(fmaxf(x * wihz + biz + sz + bhz, -30.f), 30.f);
    float r_ = __builtin_amdgcn_rcpf(1.f + __expf(-ar_));
    float z_ = __builtin_amdgcn_rcpf(1.f + __expf(-az_));
    float an_ = fminf(fmaxf(x * wihn + bin_ + r_ * (sn + bhn), -30.f), 30.f);
    float en = __expf(-2.f * an_);
    float n_ = (1.f - en) * __builtin_amdgcn_rcpf(1.f + en);
    float h_new = (1.f - z_) * n_ + z_ * h_old;
    h_old = h_new;
    if (t < S_LEN - 1) {
      // wg-scope packed 8B store -> dirty in shared XCD L2 (R8-proven)
      unsigned short hi16 = f32_to_bf16(h_new);
      unsigned short lo16 = f32_to_bf16(h_new - bf16_to_f32(hi16));
      unsigned packed = (unsigned)hi16 | ((unsigned)lo16 << 16);
      unsigned other = (unsigned)__shfl_xor((int)packed, 1);
      if ((jj & 1) == 0) {
        unsigned u0 = (packed & 0xffffu) | (other << 16);        // hi pair
        unsigned u1 = (packed >> 16) | (other & 0xffff0000u);    // lo pair
        unsigned long long wv = (unsigned long long)u0 | ((unsigned long long)u1 << 32);
        __hip_atomic_store(hq + (size_t)wr3 * HW64 + widx, wv,
                           __ATOMIC_RELAXED, __HIP_MEMORY_SCOPE_WORKGROUP);
      }
      // own-wave stores (and loads) acked at L2, then count this wave done
      asm volatile("s_waitcnt vmcnt(0)" ::: "memory");
      if (lane == 0)
        __hip_atomic_fetch_add(mycnt, 1u,
                               __ATOMIC_RELAXED, __HIP_MEMORY_SCOPE_WORKGROUP);
    }
    rd3 = wr3;
    wr3 = (wr3 == 2) ? 0 : wr3 + 1;
  }
  // --- epilogue: out[b] = h_last . fc_w + fc_b
  osum[tid] = h_old * fcw;
  __syncthreads();
  if (jj == 0) {
    float acc = 0.f;
    #pragma unroll
    for (int q = 0; q < 16; ++q) acc += osum[bb * 16 + q];
    if (s == 0) acc += fc_b[0];
    atomicAdd(&out[gb], acc);
  }
}

// ---------------------------------------------------------------------------
extern "C" void kernel_launch(void* const* d_in, const int* in_sizes, int n_in,
                              void* d_out, int out_size, void* d_ws, size_t ws_size,
                              hipStream_t stream) {
  (void)in_sizes; (void)n_in; (void)out_size; (void)ws_size;
  const int*   ends = (const int*)d_in[1];
  const float* emb  = (const float*)d_in[3];
  const float* w_ih = (const float*)d_in[4];
  const float* w_hh = (const float*)d_in[5];
  const float* b_ih = (const float*)d_in[6];
  const float* b_hh = (const float*)d_in[7];
  const float* fc_w = (const float*)d_in[8];
  const float* fc_b = (const float*)d_in[9];
  float* out = (float*)d_out;

  size_t xn_elems = (size_t)B_N * S_LEN * KP;
  unsigned short* xh = (unsigned short*)d_ws;
  unsigned short* xl = xh + xn_elems;
  float* feats = (float*)(xl + xn_elems);
  unsigned long long* hq = (unsigned long long*)(feats + S_LEN * B_N);
  unsigned int* bars = (unsigned int*)(hq + 3 * (size_t)HW64);

  hipMemsetAsync(out, 0, sizeof(float) * B_N, stream);
  hipMemsetAsync(bars, 0, 4096, stream);   // 8 groups x 32 WG wave-counters

  k1_embed_norm<<<dim3(S_LEN * B_N / 4), dim3(256), 0, stream>>>(ends, emb, xh, xl);
  k2_feats<<<dim3(8, B_N), dim3(256), 0, stream>>>(xh, xl, feats);

  void* args[] = { (void*)&feats, (void*)&w_ih, (void*)&w_hh, (void*)&b_ih,
                   (void*)&b_hh, (void*)&fc_w, (void*)&fc_b,
                   (void*)&hq, (void*)&bars, (void*)&out };
  hipLaunchCooperativeKernel((void*)k3_gru, dim3(256), dim3(256), args, 0, stream);
}

// Round 11
// 1715.322 us; speedup vs baseline: 1.2683x; 1.2683x over previous
//
#include <hip/hip_runtime.h>
#include <hip/hip_bf16.h>
#include <math.h>

// Problem: S=512, B=128, V=50257, D=300, H=512
#define S_LEN 512
#define B_N   128
#define D_EMB 300
#define KP    320   // D padded to multiple of 32 (zero-filled)
#define H_N   512

typedef __attribute__((ext_vector_type(8)))  short short8;       // 8 bf16 (4 VGPRs)
typedef __attribute__((ext_vector_type(8)))  unsigned short ushort8;
typedef __attribute__((ext_vector_type(4)))  float float4v;
typedef __attribute__((ext_vector_type(16))) float float16v;

__device__ __forceinline__ unsigned short f32_to_bf16(float f) {
  unsigned u = __float_as_uint(f);
  u = (u + 0x7fffu + ((u >> 16) & 1u)) >> 16;   // RNE
  return (unsigned short)u;
}
__device__ __forceinline__ float bf16_to_f32(unsigned short h) {
  return __uint_as_float(((unsigned)h) << 16);
}

// ---------------------------------------------------------------------------
// K1: embeds = embed_mat[ends]; xn = embeds / max(||embeds||,eps)
// writes xn as split bf16 (hi+lo), layout [b][s][KP], k 300..319 zero.
// ---------------------------------------------------------------------------
__global__ __launch_bounds__(256) void k1_embed_norm(
    const int* __restrict__ ends, const float* __restrict__ emb,
    unsigned short* __restrict__ xh, unsigned short* __restrict__ xl) {
  int wave = threadIdx.x >> 6, lane = threadIdx.x & 63;
  int vec = blockIdx.x * 4 + wave;            // vec = s*B + b (ends is [S][B])
  int b = vec & (B_N - 1), s = vec >> 7;
  int v = ends[vec];
  const float* row = emb + (size_t)v * D_EMB;
  float e0 = row[lane], e1 = row[lane + 64], e2 = row[lane + 128], e3 = row[lane + 192];
  float e4 = (lane + 256 < D_EMB) ? row[lane + 256] : 0.f;
  float ss = e0*e0 + e1*e1 + e2*e2 + e3*e3 + e4*e4;
  #pragma unroll
  for (int m = 1; m < 64; m <<= 1) ss += __shfl_xor(ss, m);
  float sc = 1.0f / fmaxf(sqrtf(ss), 1e-8f);
  size_t base = ((size_t)b * S_LEN + s) * KP;
  float xs[5] = { e0*sc, e1*sc, e2*sc, e3*sc, (lane + 256 < D_EMB) ? e4*sc : 0.f };
  #pragma unroll
  for (int i = 0; i < 5; ++i) {
    unsigned short hi = f32_to_bf16(xs[i]);
    unsigned short lo = f32_to_bf16(xs[i] - bf16_to_f32(hi));
    xh[base + lane + 64*i] = hi;
    xl[base + lane + 64*i] = lo;
  }
}

// ---------------------------------------------------------------------------
// K2: feats[i][b] = max_{j<i} dot(xn[i,b], xn[j,b]); feats[0]=0
// Split-bf16 MFMA 32x32x16 (hi*hi + hi*lo + lo*hi).
// R11: A-operand fragments loaded straight from global into registers
// (identical element mapping as the old LDS path; L2-hot after jc=0),
// LDS stages only B (22.5KB -> ~2x co-residency), grid is (b, ic) so all
// ic-chunks of a batch share one XCD L2 (same %8 mapping k3 relies on).
// ---------------------------------------------------------------------------
#define KC  80
#define LDP 88      // LDS row stride in ushorts (conflict-friendly, 16B aligned)

__global__ __launch_bounds__(256) void k2_feats(
    const unsigned short* __restrict__ xh, const unsigned short* __restrict__ xl,
    float* __restrict__ feats) {
  __shared__ __align__(16) unsigned short sBh[64*LDP], sBl[64*LDP];
  __shared__ float rbuf[4][32];
  int b   = blockIdx.x;          // 0..127 (b&7 selects XCD)
  int ic  = blockIdx.y;          // 0..7
  int tid = threadIdx.x;
  int wave = tid >> 6, lane = tid & 63;
  int itl = wave & 1, jtl = wave >> 1;
  int itg = ic * 2 + itl;        // global 32-row i-tile index
  size_t xbase = (size_t)b * S_LEN * KP;
  int arow0 = ic * 64;
  // my A row (m = lane&31) and k-quad offset
  const size_t arowoff = xbase + (size_t)(arow0 + itl * 32 + (lane & 31)) * KP
                       + (size_t)((lane >> 5) * 8);

  float rm[16];
  #pragma unroll
  for (int r = 0; r < 16; ++r) rm[r] = -INFINITY;

  for (int jc = 0; jc <= ic; ++jc) {
    int jt = jc * 2 + jtl;
    bool active = (jt <= itg);
    float16v acc;
    #pragma unroll
    for (int r = 0; r < 16; ++r) acc[r] = 0.f;

    for (int kc = 0; kc < 4; ++kc) {
      // A fragments: direct global->register (10 x 16B per lane)
      short8 a_h[5], a_l[5];
      #pragma unroll
      for (int ks = 0; ks < 5; ++ks) {
        size_t ga = arowoff + kc * KC + ks * 16;
        a_h[ks] = *(const short8*)&xh[ga];
        a_l[ks] = *(const short8*)&xl[ga];
      }
      __syncthreads();
      for (int u = tid; u < 640; u += 256) {     // 64 rows x 10 16B-segs (B only)
        int r = u / 10, sg = u % 10;
        size_t gb = xbase + (size_t)(jc*64 + r) * KP + kc*KC + sg*8;
        int la = r * LDP + sg * 8;
        *(ushort8*)&sBh[la] = *(const ushort8*)&xh[gb];
        *(ushort8*)&sBl[la] = *(const ushort8*)&xl[gb];
      }
      __syncthreads();
      if (active) {
        int br = (jtl*32 + (lane & 31)) * LDP;
        int kq = (lane >> 5) * 8;
        #pragma unroll
        for (int ks = 0; ks < 5; ++ks) {
          short8 b_h = *(const short8*)&sBh[br + ks*16 + kq];
          short8 b_l = *(const short8*)&sBl[br + ks*16 + kq];
          acc = __builtin_amdgcn_mfma_f32_32x32x16_bf16(a_h[ks], b_h, acc, 0, 0, 0);
          acc = __builtin_amdgcn_mfma_f32_32x32x16_bf16(a_h[ks], b_l, acc, 0, 0, 0);
          acc = __builtin_amdgcn_mfma_f32_32x32x16_bf16(a_l[ks], b_h, acc, 0, 0, 0);
        }
      }
    }
    if (active) {
      int colg = jt * 32 + (lane & 31);
      #pragma unroll
      for (int r = 0; r < 16; ++r) {
        int rowg = itg * 32 + (r & 3) + 8*(r >> 2) + 4*(lane >> 5);
        float v = acc[r];
        if (jt == itg && colg >= rowg) v = -INFINITY;  // causal: j<i
        rm[r] = fmaxf(rm[r], v);
      }
    }
  }
  #pragma unroll
  for (int r = 0; r < 16; ++r) {
    float v = rm[r];
    v = fmaxf(v, __shfl_xor(v, 1));
    v = fmaxf(v, __shfl_xor(v, 2));
    v = fmaxf(v, __shfl_xor(v, 4));
    v = fmaxf(v, __shfl_xor(v, 8));
    v = fmaxf(v, __shfl_xor(v, 16));
    rm[r] = v;
  }
  if ((lane & 31) == 0) {
    int half = lane >> 5;
    #pragma unroll
    for (int r = 0; r < 16; ++r)
      rbuf[wave][(r & 3) + 8*(r >> 2) + 4*half] = rm[r];
  }
  __syncthreads();
  if (tid < 64) {   // merge jt-parities, write feats
    int it2 = tid >> 5, rl = tid & 31;
    float v = fmaxf(rbuf[it2][rl], rbuf[it2 + 2][rl]);
    int i = ic * 64 + it2 * 32 + rl;
    feats[i * B_N + b] = (i == 0) ? 0.0f : v;
  }
}

// ---------------------------------------------------------------------------
// K3: GRU, persistent cooperative kernel. 256 WGs x 256 thr.
// FROZEN at the R8 skeleton (benched 1464us, absmax 0.0, 3/3 reliable):
//   wg-scope producer stores (h + flag) -> dirty in shared XCD L2
//   (WRITE_SIZE 135MB->0.5MB proven); agent-scope relaxed reads (L1-bypass,
//   L2-hit); per-WG flag bars[g*32+s]; all-wave 32-flag poll with s_sleep;
//   post-store vmcnt(0) + __syncthreads + tid0 flag store.
// LEDGER: per-wave flag fanouts fast-fail 3/3 (R5/R6/R9, mechanism unknown);
// counter-RMW flags regress (R10: atomics write through, serialize).
// ---------------------------------------------------------------------------
#define HW64 (B_N * H_N / 2)   // 8B words per buffer

__global__ __launch_bounds__(256, 1) void k3_gru(
    const float* __restrict__ feats,
    const float* __restrict__ w_ih, const float* __restrict__ w_hh,
    const float* __restrict__ b_ih, const float* __restrict__ b_hh,
    const float* __restrict__ fc_w, const float* __restrict__ fc_b,
    unsigned long long* __restrict__ hq, unsigned int* __restrict__ bars,
    float* __restrict__ out) {
  __shared__ float red[4][3][16][17];
  __shared__ float osum[256];
  int tid = threadIdx.x;
  int wave = tid >> 6, lane = tid & 63;
  int g = blockIdx.x & 7, s = blockIdx.x >> 3;

  // --- stationary W_hh fragments in registers (B-operand: n=lane&15, k=quad*8+j)
  short8 wfh[3][4], wfl[3][4];
  {
    int nloc = lane & 15;
    int kq = (lane >> 4) * 8;
    #pragma unroll
    for (int gt = 0; gt < 3; ++gt) {
      const float* wr = w_hh + (size_t)(gt * H_N + s * 16 + nloc) * H_N;
      #pragma unroll
      for (int ks = 0; ks < 4; ++ks) {
        int k0 = wave * 128 + ks * 32 + kq;
        short8 h8, l8;
        #pragma unroll
        for (int j = 0; j < 8; ++j) {
          float wv = wr[k0 + j];
          unsigned short hi = f32_to_bf16(wv);
          unsigned short lo = f32_to_bf16(wv - bf16_to_f32(hi));
          h8[j] = (short)hi; l8[j] = (short)lo;
        }
        wfh[gt][ks] = h8; wfl[gt][ks] = l8;
      }
    }
  }
  // --- per-thread gate constants: thread = (bb, jj)
  int bb = tid >> 4, jj = tid & 15;
  int jr = s * 16 + jj;
  float wihr = w_ih[jr], wihz = w_ih[H_N + jr], wihn = w_ih[2*H_N + jr];
  float bir = b_ih[jr],  biz = b_ih[H_N + jr],  bin_ = b_ih[2*H_N + jr];
  float bhr = b_hh[jr],  bhz = b_hh[H_N + jr],  bhn = b_hh[2*H_N + jr];
  float fcw = fc_w[jr];
  int gb = g * 16 + bb;
  float h_old = 0.f;
  const unsigned int* fp = bars + g * 32 + (lane & 31);  // this group's 32 flags
  unsigned int* myflag = bars + g * 32 + s;
  int arow = g * 16 + (lane & 15);              // A-operand m = batch
  int kqa = (lane >> 4) * 8;
  size_t widx = ((size_t)gb * H_N + jr) >> 1;   // 8B word index (jj even only)

  for (int t = 0; t < S_LEN; ++t) {
    // feats load hoisted above the poll — independent, overlaps the spin
    float x = feats[t * B_N + gb];
    float sr = 0.f, sz = 0.f, sn = 0.f;
    if (t > 0) {
      // ---- wait: all 32 WGs stored h_{t-1} (flag >= t). every wave polls.
      {
        const unsigned tgt = (unsigned)t;
        for (;;) {
          unsigned f = __hip_atomic_load(fp, __ATOMIC_RELAXED, __HIP_MEMORY_SCOPE_AGENT);
          if (__ballot(f < tgt) == 0ull) break;
          __builtin_amdgcn_s_sleep(1);
        }
        asm volatile("" ::: "memory");
      }
      const unsigned long long* hb =
          hq + (size_t)((t - 1) & 1) * HW64 + (size_t)arow * (H_N / 2);
      short8 ah[4], al[4];
      #pragma unroll
      for (int ks = 0; ks < 4; ++ks) {
        int kw = (wave * 128 + ks * 32 + kqa) >> 1;
        union { unsigned u[4]; short8 v; } uh, ul;
        #pragma unroll
        for (int q = 0; q < 4; ++q) {
          unsigned long long w = __hip_atomic_load(hb + kw + q,
              __ATOMIC_RELAXED, __HIP_MEMORY_SCOPE_AGENT);
          uh.u[q] = (unsigned)w;
          ul.u[q] = (unsigned)(w >> 32);
        }
        ah[ks] = uh.v; al[ks] = ul.v;
      }
      float4v a0, a1, a2;
      #pragma unroll
      for (int r = 0; r < 4; ++r) { a0[r] = 0.f; a1[r] = 0.f; a2[r] = 0.f; }
      #pragma unroll
      for (int ks = 0; ks < 4; ++ks) {
        a0 = __builtin_amdgcn_mfma_f32_16x16x32_bf16(ah[ks], wfh[0][ks], a0, 0,0,0);
        a1 = __builtin_amdgcn_mfma_f32_16x16x32_bf16(ah[ks], wfh[1][ks], a1, 0,0,0);
        a2 = __builtin_amdgcn_mfma_f32_16x16x32_bf16(ah[ks], wfh[2][ks], a2, 0,0,0);
        a0 = __builtin_amdgcn_mfma_f32_16x16x32_bf16(ah[ks], wfl[0][ks], a0, 0,0,0);
        a1 = __builtin_amdgcn_mfma_f32_16x16x32_bf16(ah[ks], wfl[1][ks], a1, 0,0,0);
        a2 = __builtin_amdgcn_mfma_f32_16x16x32_bf16(ah[ks], wfl[2][ks], a2, 0,0,0);
        a0 = __builtin_amdgcn_mfma_f32_16x16x32_bf16(al[ks], wfh[0][ks], a0, 0,0,0);
        a1 = __builtin_amdgcn_mfma_f32_16x16x32_bf16(al[ks], wfh[1][ks], a1, 0,0,0);
        a2 = __builtin_amdgcn_mfma_f32_16x16x32_bf16(al[ks], wfh[2][ks], a2, 0,0,0);
      }
      // C/D: row(batch)=(lane>>4)*4+reg, col(j)=lane&15. Scalar writes, padded.
      int colw = lane & 15, roww = (lane >> 4) * 4;
      #pragma unroll
      for (int r = 0; r < 4; ++r) {
        red[wave][0][roww + r][colw] = a0[r];
        red[wave][1][roww + r][colw] = a1[r];
        red[wave][2][roww + r][colw] = a2[r];
      }
      __syncthreads();
      sr = red[0][0][bb][jj] + red[1][0][bb][jj] + red[2][0][bb][jj] + red[3][0][bb][jj];
      sz = red[0][1][bb][jj] + red[1][1][bb][jj] + red[2][1][bb][jj] + red[3][1][bb][jj];
      sn = red[0][2][bb][jj] + red[1][2][bb][jj] + red[2][2][bb][jj] + red[3][2][bb][jj];
    }
    // gates: exact identities on fast exp; clamp to dodge inf/inf
    float ar_ = fminf(fmaxf(x * wihr + bir + sr + bhr, -30.f), 30.f);
    float az_ = fminf(fmaxf(x * wihz + biz + sz + bhz, -30.f), 30.f);
    float r_ = __builtin_amdgcn_rcpf(1.f + __expf(-ar_));
    float z_ = __builtin_amdgcn_rcpf(1.f + __expf(-az_));
    float an_ = fminf(fmaxf(x * wihn + bin_ + r_ * (sn + bhn), -30.f), 30.f);
    float en = __expf(-2.f * an_);
    float n_ = (1.f - en) * __builtin_amdgcn_rcpf(1.f + en);
    float h_new = (1.f - z_) * n_ + z_ * h_old;
    h_old = h_new;
    if (t < S_LEN - 1) {
      // WORKGROUP-scope packed 8B store: [hi(j0)|hi(j1) | lo(j0)|lo(j1)]
      unsigned short hi16 = f32_to_bf16(h_new);
      unsigned short lo16 = f32_to_bf16(h_new - bf16_to_f32(hi16));
      unsigned packed = (unsigned)hi16 | ((unsigned)lo16 << 16);
      unsigned other = (unsigned)__shfl_xor((int)packed, 1);
      if ((jj & 1) == 0) {
        unsigned u0 = (packed & 0xffffu) | (other << 16);        // hi pair
        unsigned u1 = (packed >> 16) | (other & 0xffff0000u);    // lo pair
        unsigned long long wv = (unsigned long long)u0 | ((unsigned long long)u1 << 32);
        __hip_atomic_store(hq + (size_t)(t & 1) * HW64 + widx, wv,
                           __ATOMIC_RELAXED, __HIP_MEMORY_SCOPE_WORKGROUP);
      }
      // drain own stores (ack at L2), WG barrier, then flag (wg-scope)
      asm volatile("s_waitcnt vmcnt(0)" ::: "memory");
      __syncthreads();
      if (tid == 0)
        __hip_atomic_store(myflag, (unsigned)(t + 1),
                           __ATOMIC_RELAXED, __HIP_MEMORY_SCOPE_WORKGROUP);
    }
  }
  // --- epilogue: out[b] = h_last . fc_w + fc_b
  osum[tid] = h_old * fcw;
  __syncthreads();
  if (jj == 0) {
    float acc = 0.f;
    #pragma unroll
    for (int q = 0; q < 16; ++q) acc += osum[bb * 16 + q];
    if (s == 0) acc += fc_b[0];
    atomicAdd(&out[gb], acc);
  }
}

// ---------------------------------------------------------------------------
extern "C" void kernel_launch(void* const* d_in, const int* in_sizes, int n_in,
                              void* d_out, int out_size, void* d_ws, size_t ws_size,
                              hipStream_t stream) {
  (void)in_sizes; (void)n_in; (void)out_size; (void)ws_size;
  const int*   ends = (const int*)d_in[1];
  const float* emb  = (const float*)d_in[3];
  const float* w_ih = (const float*)d_in[4];
  const float* w_hh = (const float*)d_in[5];
  const float* b_ih = (const float*)d_in[6];
  const float* b_hh = (const float*)d_in[7];
  const float* fc_w = (const float*)d_in[8];
  const float* fc_b = (const float*)d_in[9];
  float* out = (float*)d_out;

  size_t xn_elems = (size_t)B_N * S_LEN * KP;
  unsigned short* xh = (unsigned short*)d_ws;
  unsigned short* xl = xh + xn_elems;
  float* feats = (float*)(xl + xn_elems);
  unsigned long long* hq = (unsigned long long*)(feats + S_LEN * B_N);
  unsigned int* bars = (unsigned int*)(hq + 2 * (size_t)HW64);

  hipMemsetAsync(out, 0, sizeof(float) * B_N, stream);
  hipMemsetAsync(bars, 0, 4096, stream);   // 8 groups x 32 WG flags

  k1_embed_norm<<<dim3(S_LEN * B_N / 4), dim3(256), 0, stream>>>(ends, emb, xh, xl);
  k2_feats<<<dim3(B_N, 8), dim3(256), 0, stream>>>(xh, xl, feats);

  void* args[] = { (void*)&feats, (void*)&w_ih, (void*)&w_hh, (void*)&b_ih,
                   (void*)&b_hh, (void*)&fc_w, (void*)&fc_b,
                   (void*)&hq, (void*)&bars, (void*)&out };
  hipLaunchCooperativeKernel((void*)k3_gru, dim3(256), dim3(256), args, 0, stream);
}